// Round 1
// 714.018 us; speedup vs baseline: 1.1845x; 1.1845x over previous
//
#include <hip/hip_runtime.h>
#include <cstdint>
#include <cstddef>

#define E_ 8
#define T_ 1024
#define D_ 1024
#define I_ 5632
#define TWO_I_ 11264
#define NPAD_MAX 2176                 /* 2048 + 8*16 */
#define NGRP_MAX 136

// ws layout (bytes): int tables in [0,64K), then act_f, then xg_f, y overlays xg_f
#define WS_ACTF_B 65536
#define WS_XGF_B  (65536 + 24510464)              /* act_f = 136*180224      */
#define WS_Y_B    WS_XGF_B                        /* y overlays dead xg_f    */
// int-table offsets (units of 4 B)
#define WS_CNT   0
#define WS_BASEP 8
#define WS_ESLOT 16
#define WS_TOKW  2064
#define WS_ETOK  4112

typedef __attribute__((ext_vector_type(8))) __bf16 bf16x8;
typedef __attribute__((ext_vector_type(4))) float  f32x4;

__device__ __forceinline__ unsigned f2bf(float f) {
    unsigned u = __float_as_uint(f);
    u += 0x7fffu + ((u >> 16) & 1u);
    return u >> 16;
}
__device__ __forceinline__ unsigned pack2bf(float f0, float f1) {
    unsigned a0 = __float_as_uint(f0); a0 += 0x7fffu + ((a0 >> 16) & 1u);
    unsigned a1 = __float_as_uint(f1); a1 += 0x7fffu + ((a1 >> 16) & 1u);
    return (a0 >> 16) | (a1 & 0xffff0000u);
}

// ---------------------------------------------------------------- routing ---
__global__ void routing_kernel(const float* __restrict__ gate,
                               int* cnt, int* basep, int* eslot,
                               float* tokw, int* etok)
{
    int t = threadIdx.x;
    if (t < E_) cnt[t] = 0;
    __syncthreads();
    float g[E_];
#pragma unroll
    for (int e = 0; e < E_; ++e) g[e] = gate[t * E_ + e];
    int i0 = 0; float p0 = g[0];
#pragma unroll
    for (int e = 1; e < E_; ++e) if (g[e] > p0) { p0 = g[e]; i0 = e; }
    int i1 = -1; float p1 = -1e30f;
#pragma unroll
    for (int e = 0; e < E_; ++e) if (e != i0 && g[e] > p1) { p1 = g[e]; i1 = e; }
    float w0 = 1.0f / (1.0f + expf(p1 - p0));
    float w1 = 1.0f - w0;
    int s0 = atomicAdd(&cnt[i0], 1);
    int s1 = atomicAdd(&cnt[i1], 1);
    etok[i0 * T_ + s0] = t;
    etok[i1 * T_ + s1] = t;
    eslot[t * 2 + 0] = i0 * T_ + s0;  tokw[t * 2 + 0] = w0;
    eslot[t * 2 + 1] = i1 * T_ + s1;  tokw[t * 2 + 1] = w1;
    __syncthreads();
    if (t == 0) {
        int r = 0;
#pragma unroll
        for (int e = 0; e < E_; ++e) { basep[e] = r; r += (cnt[e] + 15) & ~15; }
    }
}

// ------------------- gather x rows, cast bf16, fragment-major swizzle -------
__global__ void gather_cast_kernel(const float* __restrict__ x,
                                   const int* __restrict__ cnt,
                                   const int* __restrict__ basep,
                                   const int* __restrict__ etok,
                                   unsigned short* __restrict__ xgf)
{
    int e = blockIdx.x >> 6, g = blockIdx.x & 63;
    int n = cnt[e];
    if (g * 16 >= n) return;
    int tid = threadIdx.x;
    int row = g * 16 + (tid & 15);
    row = min(row, n - 1);
    int tok = etok[e * T_ + row];
    const float* xr = x + (size_t)tok * D_;
    unsigned short* dst = xgf + ((size_t)(basep[e] >> 4) + g) * 16384;
#pragma unroll
    for (int it = 0; it < 8; ++it) {
        int c = it * 16 + (tid >> 4);          // k-chunk 0..127
        float4 v0 = *(const float4*)(xr + c * 8);
        float4 v1 = *(const float4*)(xr + c * 8 + 4);
        uint4 h;
        h.x = pack2bf(v0.x, v0.y); h.y = pack2bf(v0.z, v0.w);
        h.z = pack2bf(v1.x, v1.y); h.w = pack2bf(v1.z, v1.w);
        *(uint4*)(dst + c * 128 + (tid & 15) * 8) = h;
    }
}

// ------------------------------------------------- gemm1: xg@w1 + silu -----
// grid = E_*176, block 4 waves. B path: LDS-staged transpose+dequant.
// Per K-step (32 k x 64 cols = 8 KB int32): 256 thr x 8 coalesced dwords
// (lane->col), dequant 8 vals, one ds_write_b128 into MFMA-fragment-order
// LDS tile (4 KB, double-buffered). Compute: 2 ds_read_b128 per wave/step
// replaces the old 16 scattered dword loads + 80 dequant VALU/step.
// A stays direct-from-global (xgf is L2/L3-hot, 4.5 MB).
__global__ __launch_bounds__(256, 2) void gemm1_kernel(
    const unsigned short* __restrict__ xgf, const int* __restrict__ w1q,
    const float* __restrict__ w1s, const int* __restrict__ cnt,
    const int* __restrict__ basep, unsigned short* __restrict__ actf)
{
    __shared__ unsigned char blds[2][4096];
    int cg = blockIdx.x % 176, e = blockIdx.x / 176;
    int n = cnt[e];
    if (n <= 0) return;
    int npad = (n + 15) & ~15;
    int pb = basep[e];
    int tid = threadIdx.x, lane = tid & 63, w = tid >> 6;
    int l15 = lane & 15, lq = lane >> 4;
    int colg = w & 1, mh = w >> 1;
    int jcol = cg * 32 + colg * 16 + l15;

    // staging-side role: thread -> (column, k-subgroup)
    int col64 = tid & 63, kg = tid >> 6;
    int jb = (col64 < 32) ? (cg * 32 + col64) : (I_ + cg * 32 + (col64 - 32));
    const int*   gq  = w1q + ((size_t)e * 1024 + kg * 8) * TWO_I_ + jb;
    const float* sqp = w1s + (size_t)e * 8 * TWO_I_ + jb;
    // LDS fragment layout: [c = col64/16][lane' = kg*16 + col64%16][j=k%8]
    unsigned swr = (unsigned)(col64 >> 4) * 1024 + (unsigned)(kg * 16 + (col64 & 15)) * 16;
    unsigned srd = (unsigned)colg * 1024 + (unsigned)lane * 16;   // gate frag; up at +2048

    int P0[8], P1[8];
    float sc = 0.f, oc = 0.f;

#define G1_ISSUE(KS, P)                                                     \
    { _Pragma("unroll")                                                     \
      for (int i_ = 0; i_ < 8; ++i_)                                        \
          P[i_] = gq[(size_t)((KS) * 32 + i_) * TWO_I_]; }

#define G1_DEQW(KS, P)                                                      \
    { if (((KS) & 3) == 0) { sc = sqp[(size_t)((KS) >> 2) * TWO_I_];        \
                             oc = -8.f * sc; }                              \
      uint4 fr_;                                                            \
      fr_.x = pack2bf((float)P[0]*sc + oc, (float)P[1]*sc + oc);            \
      fr_.y = pack2bf((float)P[2]*sc + oc, (float)P[3]*sc + oc);            \
      fr_.z = pack2bf((float)P[4]*sc + oc, (float)P[5]*sc + oc);            \
      fr_.w = pack2bf((float)P[6]*sc + oc, (float)P[7]*sc + oc);            \
      *(uint4*)(&blds[(KS) & 1][swr]) = fr_; }

    for (int tb = 0; tb < npad; tb += 320) {
        int aoff[10];
#pragma unroll
        for (int mi = 0; mi < 10; ++mi) {
            int R = tb + mh * 160 + mi * 16;
            R = min(R, npad - 16);
            aoff[mi] = ((pb + R) >> 4) * 32768;
        }
        const char* abase = (const char*)xgf + lq * 256 + l15 * 16;

        f32x4 accg[10], accu[10];
#pragma unroll
        for (int mi = 0; mi < 10; ++mi) {
            accg[mi] = (f32x4){0.f, 0.f, 0.f, 0.f};
            accu[mi] = (f32x4){0.f, 0.f, 0.f, 0.f};
        }
        G1_ISSUE(0, P0);
        G1_ISSUE(1, P1);
        G1_DEQW(0, P0);          // fills buf0 for ks=0
        G1_ISSUE(2, P0);
        __syncthreads();

#pragma unroll 2
        for (int ks = 0; ks < 32; ++ks) {
            const char* at = abase + ks * 1024;
            bf16x8 a[10];
#pragma unroll
            for (int mi = 0; mi < 10; ++mi)
                a[mi] = *(const bf16x8*)(at + aoff[mi]);
            bf16x8 bg = *(const bf16x8*)(&blds[ks & 1][srd]);
            bf16x8 bu = *(const bf16x8*)(&blds[ks & 1][srd + 2048]);
            // stage next step into the other buffer; prefetch 2 steps deep
            if (ks < 31) {
                if (ks & 1) {
                    G1_DEQW(ks + 1, P0);
                    if (ks < 29) { G1_ISSUE(ks + 3, P0); }
                } else {
                    G1_DEQW(ks + 1, P1);
                    if (ks < 29) { G1_ISSUE(ks + 3, P1); }
                }
            }
#pragma unroll
            for (int mi = 0; mi < 10; ++mi) {
                accg[mi] = __builtin_amdgcn_mfma_f32_16x16x32_bf16(a[mi], bg, accg[mi], 0, 0, 0);
                accu[mi] = __builtin_amdgcn_mfma_f32_16x16x32_bf16(a[mi], bu, accu[mi], 0, 0, 0);
            }
            __syncthreads();
        }
        // epilogue: silu(gate)*up -> act_f fragment-major
#pragma unroll
        for (int mi = 0; mi < 10; ++mi) {
#pragma unroll
            for (int r = 0; r < 4; ++r) {
                int ml = mh * 160 + mi * 16 + lq * 4 + r;
                int m = tb + ml;
                if (m < npad) {
                    float gv = accg[mi][r], uv = accu[mi][r];
                    float av = gv / (1.f + __expf(-gv)) * uv;
                    int prow = pb + m;
                    size_t o = (size_t)(prow >> 4) * 90112 + (jcol >> 3) * 128
                             + (prow & 15) * 8 + (jcol & 7);
                    actf[o] = (unsigned short)f2bf(av);
                }
            }
        }
    }
#undef G1_ISSUE
#undef G1_DEQW
}

// ---------------------------------------------------- gemm2: act@w2 --------
// grid = E_*16dt*4seg = 512 blocks. Same LDS-staged dequant structure as
// gemm1: per step 32k x 64cols, thread loads 8 coalesced dwords (256 B
// contiguous per wave-inst), one ds_write_b128 in fragment order.
__global__ __launch_bounds__(256, 2) void gemm2_kernel(
    const unsigned short* __restrict__ actf, const int* __restrict__ w2q,
    const float* __restrict__ w2s, const int* __restrict__ cnt,
    const int* __restrict__ basep, float* __restrict__ y)
{
    __shared__ unsigned char blds[2][4096];
    int bid = blockIdx.x;
    int seg = bid & 3, dt = (bid >> 2) & 15, e = bid >> 6;
    int n = cnt[e];
    if (n <= 0) return;
    int npad = (n + 15) & ~15;
    int pb = basep[e];
    int tid = threadIdx.x, lane = tid & 63, w = tid >> 6;
    int l15 = lane & 15, lq = lane >> 4;
    int colg = w & 1, mh = w >> 1;
    int dcol = dt * 64 + colg * 32 + l15;      // second frag col = dcol + 16

    int col64 = tid & 63, kg = tid >> 6;
    int colb = dt * 64 + col64;
    const int*   gq  = w2q + ((size_t)e * 5632 + seg * 1408 + kg * 8) * 1024 + colb;
    const float* sqp = w2s + ((size_t)e * 44 + seg * 11) * 1024 + colb;
    unsigned swr = (unsigned)(col64 >> 4) * 1024 + (unsigned)(kg * 16 + (col64 & 15)) * 16;
    unsigned srd = (unsigned)(colg * 2) * 1024 + (unsigned)lane * 16;  // frag0; frag1 at +1024

    int P0[8], P1[8];
    float sc = 0.f, oc = 0.f;

#define G2_ISSUE(KS, P)                                                     \
    { _Pragma("unroll")                                                     \
      for (int i_ = 0; i_ < 8; ++i_)                                        \
          P[i_] = gq[(size_t)((KS) * 32 + i_) * 1024]; }

#define G2_DEQW(KS, P)                                                      \
    { if (((KS) & 3) == 0) { sc = sqp[(size_t)((KS) >> 2) * 1024];          \
                             oc = -8.f * sc; }                              \
      uint4 fr_;                                                            \
      fr_.x = pack2bf((float)P[0]*sc + oc, (float)P[1]*sc + oc);            \
      fr_.y = pack2bf((float)P[2]*sc + oc, (float)P[3]*sc + oc);            \
      fr_.z = pack2bf((float)P[4]*sc + oc, (float)P[5]*sc + oc);            \
      fr_.w = pack2bf((float)P[6]*sc + oc, (float)P[7]*sc + oc);            \
      *(uint4*)(&blds[(KS) & 1][swr]) = fr_; }

    for (int tb = 0; tb < npad; tb += 320) {
        int aoff[10];
#pragma unroll
        for (int mi = 0; mi < 10; ++mi) {
            int R = tb + mh * 160 + mi * 16;
            R = min(R, npad - 16);
            aoff[mi] = ((pb + R) >> 4) * 180224;
        }
        const char* abase = (const char*)actf + seg * 45056 + lq * 256 + l15 * 16;

        f32x4 acc0[10], acc1[10];
#pragma unroll
        for (int mi = 0; mi < 10; ++mi) {
            acc0[mi] = (f32x4){0.f, 0.f, 0.f, 0.f};
            acc1[mi] = (f32x4){0.f, 0.f, 0.f, 0.f};
        }
        G2_ISSUE(0, P0);
        G2_ISSUE(1, P1);
        G2_DEQW(0, P0);
        G2_ISSUE(2, P0);
        __syncthreads();

#pragma unroll 2
        for (int ks = 0; ks < 44; ++ks) {
            const char* at = abase + ks * 1024;
            bf16x8 a[10];
#pragma unroll
            for (int mi = 0; mi < 10; ++mi)
                a[mi] = *(const bf16x8*)(at + aoff[mi]);
            bf16x8 b0 = *(const bf16x8*)(&blds[ks & 1][srd]);
            bf16x8 b1 = *(const bf16x8*)(&blds[ks & 1][srd + 1024]);
            if (ks < 43) {
                if (ks & 1) {
                    G2_DEQW(ks + 1, P0);
                    if (ks < 41) { G2_ISSUE(ks + 3, P0); }
                } else {
                    G2_DEQW(ks + 1, P1);
                    if (ks < 41) { G2_ISSUE(ks + 3, P1); }
                }
            }
#pragma unroll
            for (int mi = 0; mi < 10; ++mi) {
                acc0[mi] = __builtin_amdgcn_mfma_f32_16x16x32_bf16(a[mi], b0, acc0[mi], 0, 0, 0);
                acc1[mi] = __builtin_amdgcn_mfma_f32_16x16x32_bf16(a[mi], b1, acc1[mi], 0, 0, 0);
            }
            __syncthreads();
        }
#pragma unroll
        for (int mi = 0; mi < 10; ++mi) {
#pragma unroll
            for (int r = 0; r < 4; ++r) {
                int m = tb + mh * 160 + mi * 16 + lq * 4 + r;
                if (m < n) {
                    float* yr = y + (size_t)seg * NPAD_MAX * 1024 + (size_t)(pb + m) * 1024;
                    yr[dcol]      = acc0[mi][r];
                    yr[dcol + 16] = acc1[mi][r];
                }
            }
        }
    }
#undef G2_ISSUE
#undef G2_DEQW
}

// --------------------------------------------------------------- combine ---
__global__ void combine_kernel(const float* __restrict__ y,
                               const int* __restrict__ eslot,
                               const float* __restrict__ tokw,
                               const int* __restrict__ basep,
                               float* __restrict__ out)
{
    int idx = blockIdx.x * blockDim.x + threadIdx.x;
    int t  = idx >> 8;
    int dc = idx & 255;
    int es0 = eslot[t * 2 + 0], es1 = eslot[t * 2 + 1];
    float w0 = tokw[t * 2 + 0], w1 = tokw[t * 2 + 1];
    int p0 = basep[es0 >> 10] + (es0 & 1023);
    int p1 = basep[es1 >> 10] + (es1 & 1023);
    const float4* y4 = (const float4*)y;
    float4 o = (float4){0.f, 0.f, 0.f, 0.f};
#pragma unroll
    for (int seg = 0; seg < 4; ++seg) {
        float4 a = y4[((size_t)seg * NPAD_MAX + p0) * 256 + dc];
        float4 b = y4[((size_t)seg * NPAD_MAX + p1) * 256 + dc];
        o.x += w0 * a.x + w1 * b.x;
        o.y += w0 * a.y + w1 * b.y;
        o.z += w0 * a.z + w1 * b.z;
        o.w += w0 * a.w + w1 * b.w;
    }
    ((float4*)out)[idx] = o;
}

// ---------------------------------------------------------------- launch ---
extern "C" void kernel_launch(void* const* d_in, const int* in_sizes, int n_in,
                              void* d_out, int out_size, void* d_ws, size_t ws_size,
                              hipStream_t stream)
{
    const float* x    = (const float*)d_in[0];
    const float* gate = (const float*)d_in[1];
    const int*   w1q  = (const int*)d_in[2];
    const int*   w2q  = (const int*)d_in[3];
    const float* w1s  = (const float*)d_in[4];
    const float* w2s  = (const float*)d_in[5];
    float* out = (float*)d_out;
    int*   wsi = (int*)d_ws;
    float* wsf = (float*)d_ws;

    int*   cnt   = wsi + WS_CNT;
    int*   basep = wsi + WS_BASEP;
    int*   eslot = wsi + WS_ESLOT;
    float* tokw  = wsf + WS_TOKW;
    int*   etok  = wsi + WS_ETOK;
    unsigned short* actf = (unsigned short*)((char*)d_ws + WS_ACTF_B);
    unsigned short* xgf  = (unsigned short*)((char*)d_ws + WS_XGF_B);
    float*          y    = (float*)((char*)d_ws + WS_Y_B);

    routing_kernel<<<1, 1024, 0, stream>>>(gate, cnt, basep, eslot, tokw, etok);
    gather_cast_kernel<<<E_ * 64, 256, 0, stream>>>(x, cnt, basep, etok, xgf);
    gemm1_kernel<<<E_ * 176, 256, 0, stream>>>(xgf, w1q, w1s, cnt, basep, actf);
    gemm2_kernel<<<E_ * 16 * 4, 256, 0, stream>>>(actf, w2q, w2s, cnt, basep, y);
    combine_kernel<<<(T_ * D_ / 4) / 256, 256, 0, stream>>>(y, eslot, tokw, basep, out);
}